// Round 1
// baseline (2619.735 us; speedup 1.0000x reference)
//
#include <hip/hip_runtime.h>
#include <math.h>

#define BB 64
#define TT 32
#define II 512
#define HH 256
#define ZN 1024   // 4*H
#define OO 512
#define NPRE 25

// ---------------------------------------------------------------------------
// Tiled transpose: src [1024][256] -> dst[w] [256][1024]  (whhT[k][zc])
// ---------------------------------------------------------------------------
__global__ __launch_bounds__(256) void transpose_whh(
    const float* __restrict__ s0, const float* __restrict__ s1,
    const float* __restrict__ s2, const float* __restrict__ s3,
    float* __restrict__ dst)
{
    __shared__ float tile[32][33];
    const int w = blockIdx.z;
    const float* src = (w == 0) ? s0 : (w == 1) ? s1 : (w == 2) ? s2 : s3;
    float* out = dst + (size_t)w * (HH * ZN);
    const int k0  = blockIdx.x * 32;   // over 256
    const int zc0 = blockIdx.y * 32;   // over 1024
    const int tx = threadIdx.x, ty = threadIdx.y;  // (32,8)
    #pragma unroll
    for (int i = 0; i < 32; i += 8)
        tile[ty + i][tx] = src[(size_t)(zc0 + ty + i) * HH + k0 + tx];
    __syncthreads();
    #pragma unroll
    for (int i = 0; i < 32; i += 8)
        out[(size_t)(k0 + ty + i) * ZN + zc0 + tx] = tile[tx][ty + i];
}

// ---------------------------------------------------------------------------
// GEMM: C[m,n] = sum_k A[m*lda+k] * W[n*ldw+k] + bias[n]
// 64x64 tile, BK=16, 256 threads, 4x4 micro-tile
// ---------------------------------------------------------------------------
__global__ __launch_bounds__(256) void gemm_nt(
    const float* __restrict__ A, int lda,
    const float* __restrict__ W, int ldw,
    const float* __restrict__ bias,
    float* __restrict__ C, int ldc,
    int M, int N, int K)
{
    __shared__ float As[16][68];
    __shared__ float Ws[16][68];
    const int tid = threadIdx.x;
    const int bm = blockIdx.y * 64;
    const int bn = blockIdx.x * 64;
    const int tx = tid & 15, ty = tid >> 4;
    const int lr = tid >> 2;
    const int lc = (tid & 3) << 2;
    float acc[4][4];
    #pragma unroll
    for (int i = 0; i < 4; ++i)
        #pragma unroll
        for (int j = 0; j < 4; ++j) acc[i][j] = 0.f;

    for (int k0 = 0; k0 < K; k0 += 16) {
        const float4 av = *(const float4*)(A + (size_t)(bm + lr) * lda + k0 + lc);
        const float4 wv = *(const float4*)(W + (size_t)(bn + lr) * ldw + k0 + lc);
        As[lc + 0][lr] = av.x; As[lc + 1][lr] = av.y; As[lc + 2][lr] = av.z; As[lc + 3][lr] = av.w;
        Ws[lc + 0][lr] = wv.x; Ws[lc + 1][lr] = wv.y; Ws[lc + 2][lr] = wv.z; Ws[lc + 3][lr] = wv.w;
        __syncthreads();
        #pragma unroll
        for (int k = 0; k < 16; ++k) {
            const float4 a = *(const float4*)&As[k][ty * 4];
            const float4 b = *(const float4*)&Ws[k][tx * 4];
            const float a_[4] = {a.x, a.y, a.z, a.w};
            const float b_[4] = {b.x, b.y, b.z, b.w};
            #pragma unroll
            for (int i = 0; i < 4; ++i)
                #pragma unroll
                for (int j = 0; j < 4; ++j)
                    acc[i][j] = fmaf(a_[i], b_[j], acc[i][j]);
        }
        __syncthreads();
    }
    #pragma unroll
    for (int i = 0; i < 4; ++i) {
        float4 o;
        o.x = acc[i][0] + bias[bn + tx * 4 + 0];
        o.y = acc[i][1] + bias[bn + tx * 4 + 1];
        o.z = acc[i][2] + bias[bn + tx * 4 + 2];
        o.w = acc[i][3] + bias[bn + tx * 4 + 3];
        *(float4*)(C + (size_t)(bm + ty * 4 + i) * ldc + bn + tx * 4) = o;
    }
}

// ---------------------------------------------------------------------------
// Recurrence: 56 runs x 4 batch-chunks of 16 rows. One WG per (run, chunk).
// Per step: z[16,1024] = xg[:,t,:] + h @ whh^T ; gates ; pooling/seq output.
// whhT is pre-transposed: whhT[k][zc].
// run ids:
//   0        : L1 fwd full  (running max -> prefix_pool fwd half, t=0..24)
//   1        : L1 bwd full  (running max -> suffix_pool bwd half, t=25..1)
//   2..26    : L1 bwd prefix runs len=1..25 (end max -> prefix_pool bwd half)
//   27..51   : L1 fwd suffix runs len=1..25 (end max -> suffix_pool fwd half)
//   52..55   : L2 runs (r2f, r2b, r3f, r3b) -> r4 sequence buffer
// ---------------------------------------------------------------------------
__device__ __forceinline__ float sigm_(float x) { return 1.f / (1.f + __expf(-x)); }
__device__ __forceinline__ float tanh_(float x) { return 1.f - 2.f / (__expf(2.f * x) + 1.f); }

__global__ __launch_bounds__(256) void lstm_runs(
    const float* __restrict__ ws_xgf,
    const float* __restrict__ ws_xgb,
    const float* __restrict__ ws_xg2,
    const float* __restrict__ whfT, const float* __restrict__ whbT,
    const float* __restrict__ w2fT, const float* __restrict__ w2bT,
    float* __restrict__ out_pre,
    float* __restrict__ out_suf,
    float* __restrict__ r4buf)
{
    __shared__ float h_lds[16][HH];    // 16 KB
    __shared__ float w_lds[16][ZN];    // 64 KB (gfx950 LDS = 160 KB/CU)

    const int wg  = blockIdx.x;
    const int rid = wg >> 2;
    const int b0  = (wg & 3) * 16;
    const int tid = threadIdx.x;
    const int q   = tid & 63;          // H-col group: cols q*4..q*4+3
    const int rg  = tid >> 6;          // wave id: rows rg*4..rg*4+3
    const int q4  = q << 2;
    const int rg4 = rg << 2;

    const float* xg; const float* whT;
    int t0, dt, ns, mode, len = 0, part = 0;
    if (rid == 0)      { xg = ws_xgf; whT = whfT; t0 = 0;  dt = 1;  ns = 32; mode = 0; }
    else if (rid == 1) { xg = ws_xgb; whT = whbT; t0 = 31; dt = -1; ns = 32; mode = 1; }
    else if (rid < 27) { len = rid - 1;  xg = ws_xgb; whT = whbT; t0 = len - 1; dt = -1; ns = len;      mode = 2; }
    else if (rid < 52) { len = rid - 26; xg = ws_xgf; whT = whfT; t0 = len;     dt = 1;  ns = 32 - len; mode = 3; }
    else {
        part = rid - 52;
        xg = ws_xg2 + (size_t)part * (BB * TT * ZN);
        whT = (part & 1) ? w2bT : w2fT;
        if (part & 1) { t0 = 31; dt = -1; } else { t0 = 0; dt = 1; }
        ns = 32; mode = 4;
    }

    float cst[4][4], mx[4][4];
    #pragma unroll
    for (int i = 0; i < 4; ++i)
        #pragma unroll
        for (int j = 0; j < 4; ++j) { cst[i][j] = 0.f; mx[i][j] = -3.4e38f; }

    for (int i = tid; i < 16 * HH; i += 256) (&h_lds[0][0])[i] = 0.f;
    __syncthreads();

    for (int s = 0; s < ns; ++s) {
        const int t = t0 + dt * s;

        // z init from precomputed input-gate activations
        float z[4][16];   // [ri][g*4+ci]
        #pragma unroll
        for (int ri = 0; ri < 4; ++ri) {
            const int b = b0 + rg4 + ri;
            const float* xp = xg + ((size_t)b * TT + t) * ZN + q4;
            #pragma unroll
            for (int g = 0; g < 4; ++g) {
                const float4 v = *(const float4*)(xp + g * 256);
                z[ri][g * 4 + 0] = v.x; z[ri][g * 4 + 1] = v.y;
                z[ri][g * 4 + 2] = v.z; z[ri][g * 4 + 3] = v.w;
            }
        }

        // z += h @ whh^T, staged through LDS in 16-wide K slabs
        for (int k0 = 0; k0 < HH; k0 += 16) {
            #pragma unroll
            for (int p = 0; p < 16; ++p) {
                const int f4  = tid + 256 * p;
                const int kk  = f4 >> 8;
                const int zc4 = (f4 & 255) << 2;
                *(float4*)&w_lds[kk][zc4] = *(const float4*)(whT + (size_t)(k0 + kk) * ZN + zc4);
            }
            __syncthreads();
            #pragma unroll
            for (int kk = 0; kk < 16; ++kk) {
                float hv[4];
                #pragma unroll
                for (int ri = 0; ri < 4; ++ri) hv[ri] = h_lds[rg4 + ri][k0 + kk];
                #pragma unroll
                for (int g = 0; g < 4; ++g) {
                    const float4 w = *(const float4*)&w_lds[kk][(g << 8) + q4];
                    const float w_[4] = {w.x, w.y, w.z, w.w};
                    #pragma unroll
                    for (int ri = 0; ri < 4; ++ri)
                        #pragma unroll
                        for (int ci = 0; ci < 4; ++ci)
                            z[ri][g * 4 + ci] = fmaf(hv[ri], w_[ci], z[ri][g * 4 + ci]);
                }
            }
            __syncthreads();
        }

        // gates (i, f, g, o) + state update + running max
        float h2[4][4];
        #pragma unroll
        for (int ri = 0; ri < 4; ++ri) {
            #pragma unroll
            for (int ci = 0; ci < 4; ++ci) {
                const float iv = z[ri][0 + ci];
                const float fv = z[ri][4 + ci];
                const float gv = z[ri][8 + ci];
                const float ov = z[ri][12 + ci];
                const float c2 = sigm_(fv) * cst[ri][ci] + sigm_(iv) * tanh_(gv);
                const float hh = sigm_(ov) * tanh_(c2);
                cst[ri][ci] = c2;
                h2[ri][ci] = hh;
                mx[ri][ci] = fmaxf(mx[ri][ci], hh);
            }
        }

        // publish h for next step (prior barrier guarantees all reads done)
        #pragma unroll
        for (int ri = 0; ri < 4; ++ri)
            *(float4*)&h_lds[rg4 + ri][q4] =
                make_float4(h2[ri][0], h2[ri][1], h2[ri][2], h2[ri][3]);

        // outputs
        if (mode == 0) {
            if (t <= 24) {
                #pragma unroll
                for (int ri = 0; ri < 4; ++ri) {
                    const int b = b0 + rg4 + ri;
                    *(float4*)(out_pre + ((size_t)t * BB + b) * (2 * HH) + q4) =
                        make_float4(mx[ri][0], mx[ri][1], mx[ri][2], mx[ri][3]);
                }
            }
        } else if (mode == 1) {
            if (t >= 1 && t <= 25) {
                #pragma unroll
                for (int ri = 0; ri < 4; ++ri) {
                    const int b = b0 + rg4 + ri;
                    *(float4*)(out_suf + ((size_t)(t - 1) * BB + b) * (2 * HH) + HH + q4) =
                        make_float4(mx[ri][0], mx[ri][1], mx[ri][2], mx[ri][3]);
                }
            }
        } else if (mode == 2) {
            if (s == ns - 1) {
                #pragma unroll
                for (int ri = 0; ri < 4; ++ri) {
                    const int b = b0 + rg4 + ri;
                    *(float4*)(out_pre + ((size_t)(len - 1) * BB + b) * (2 * HH) + HH + q4) =
                        make_float4(mx[ri][0], mx[ri][1], mx[ri][2], mx[ri][3]);
                }
            }
        } else if (mode == 3) {
            if (s == ns - 1) {
                #pragma unroll
                for (int ri = 0; ri < 4; ++ri) {
                    const int b = b0 + rg4 + ri;
                    *(float4*)(out_suf + ((size_t)(len - 1) * BB + b) * (2 * HH) + q4) =
                        make_float4(mx[ri][0], mx[ri][1], mx[ri][2], mx[ri][3]);
                }
            }
        } else {
            #pragma unroll
            for (int ri = 0; ri < 4; ++ri) {
                const int b = b0 + rg4 + ri;
                *(float4*)(r4buf + ((size_t)b * TT + t) * ZN + part * HH + q4) =
                    make_float4(h2[ri][0], h2[ri][1], h2[ri][2], h2[ri][3]);
            }
        }
        // next step's first __syncthreads (after staging) fences h_lds writes
    }
}

// ---------------------------------------------------------------------------
extern "C" void kernel_launch(void* const* d_in, const int* in_sizes, int n_in,
                              void* d_out, int out_size, void* d_ws, size_t ws_size,
                              hipStream_t stream)
{
    const float* x    = (const float*)d_in[0];
    const float* wif  = (const float*)d_in[1];
    const float* whf  = (const float*)d_in[2];
    const float* bf   = (const float*)d_in[3];
    const float* wib  = (const float*)d_in[4];
    const float* whb  = (const float*)d_in[5];
    const float* bb   = (const float*)d_in[6];
    const float* w2if = (const float*)d_in[7];
    const float* w2hf = (const float*)d_in[8];
    const float* b2f  = (const float*)d_in[9];
    const float* w2ib = (const float*)d_in[10];
    const float* w2hb = (const float*)d_in[11];
    const float* b2b  = (const float*)d_in[12];
    const float* wl   = (const float*)d_in[13];
    const float* bl   = (const float*)d_in[14];

    const size_t XG = (size_t)BB * TT * ZN;      // 2,097,152 floats
    float* ws  = (float*)d_ws;
    float* xgf = ws;
    float* xgb = xgf + XG;
    float* xg2 = xgb + XG;                       // 4 consecutive arrays
    float* r4  = xg2 + 4 * XG;
    float* whT = r4 + XG;                        // 4 x [256][1024]

    float* outp    = (float*)d_out;
    float* out_pre = outp + (size_t)BB * TT * OO;
    float* out_suf = out_pre + (size_t)NPRE * BB * (2 * HH);

    // 1. pre-transpose recurrent weights -> whhT[k][zc]
    transpose_whh<<<dim3(8, 32, 4), dim3(32, 8), 0, stream>>>(whf, whb, w2hf, w2hb, whT);

    // 2. input-gate activation GEMMs (mask-independent: computed once)
    const dim3 blk(256);
    gemm_nt<<<dim3(16, 32), blk, 0, stream>>>(x, II, wif, II, bf, xgf, ZN, BB * TT, ZN, II);
    gemm_nt<<<dim3(16, 32), blk, 0, stream>>>(x, II, wib, II, bb, xgb, ZN, BB * TT, ZN, II);
    gemm_nt<<<dim3(16, 32), blk, 0, stream>>>(x,      II, w2if, HH, b2f, xg2 + 0 * XG, ZN, BB * TT, ZN, HH);
    gemm_nt<<<dim3(16, 32), blk, 0, stream>>>(x,      II, w2ib, HH, b2b, xg2 + 1 * XG, ZN, BB * TT, ZN, HH);
    gemm_nt<<<dim3(16, 32), blk, 0, stream>>>(x + HH, II, w2if, HH, b2f, xg2 + 2 * XG, ZN, BB * TT, ZN, HH);
    gemm_nt<<<dim3(16, 32), blk, 0, stream>>>(x + HH, II, w2ib, HH, b2b, xg2 + 3 * XG, ZN, BB * TT, ZN, HH);

    // 3. all 56 LSTM runs (structure-collapsed from 50 masked BiLSTMs + layer 2)
    lstm_runs<<<dim3(224), blk, 0, stream>>>(xgf, xgb, xg2,
        whT + 0 * (HH * ZN), whT + 1 * (HH * ZN), whT + 2 * (HH * ZN), whT + 3 * (HH * ZN),
        out_pre, out_suf, r4);

    // 4. final projection: output = r4 @ wl^T + bl
    gemm_nt<<<dim3(8, 32), blk, 0, stream>>>(r4, ZN, wl, ZN, bl, outp, OO, BB * TT, OO, ZN);
}

// Round 2
// 924.570 us; speedup vs baseline: 2.8335x; 2.8335x over previous
//
#include <hip/hip_runtime.h>
#include <math.h>

#define BB 64
#define TT 32
#define II 512
#define HH 256
#define ZN 1024   // 4*H
#define OO 512
#define NPRE 25

typedef unsigned short u16;
typedef short bfrag __attribute__((ext_vector_type(8)));   // 8 bf16 (4 VGPRs)
typedef float f32x4 __attribute__((ext_vector_type(4)));

__device__ __forceinline__ float sigm_(float x) { return 1.f / (1.f + __expf(-x)); }
__device__ __forceinline__ float tanh_(float x) { return 1.f - 2.f / (__expf(2.f * x) + 1.f); }

__device__ __forceinline__ u16 f2bf(float x) {
    union { float f; unsigned u; } v; v.f = x;
    unsigned r = v.u + 0x7fffu + ((v.u >> 16) & 1u);   // RNE
    return (u16)(r >> 16);
}
__device__ __forceinline__ float bf2f(u16 b) {
    union { unsigned u; float f; } v; v.u = ((unsigned)b) << 16; return v.f;
}

// ---------------------------------------------------------------------------
// One-time weight prep: whh [1024(zc)][256(k)] fp32 ->
//   MFMA-B-fragment-linear bf16 hi/lo:  idx = ((kt*64 + nt)*64 + l)*8 + i
//   holds Wt[k = kt*32 + (l>>4)*8 + i][zc = nt*16 + (l&15)] = whh[zc][k]
// ---------------------------------------------------------------------------
__global__ __launch_bounds__(256) void prep_weights(
    const float* __restrict__ whf, const float* __restrict__ whb,
    const float* __restrict__ w2f, const float* __restrict__ w2b,
    u16* __restrict__ Whi, u16* __restrict__ Wlo)
{
    const int m = blockIdx.y;
    const float* src = (m == 0) ? whf : (m == 1) ? whb : (m == 2) ? w2f : w2b;
    const int e = blockIdx.x * 256 + threadIdx.x;      // 0..262143
    const int i  = e & 7;
    const int l  = (e >> 3) & 63;
    const int nt = (e >> 9) & 63;
    const int kt = e >> 15;
    const int zc = nt * 16 + (l & 15);
    const int k  = kt * 32 + ((l >> 4) << 3) + i;
    const float v = src[(size_t)zc * HH + k];
    const u16 hi = f2bf(v);
    const u16 lo = f2bf(v - bf2f(hi));
    Whi[(size_t)m * 262144 + e] = hi;
    Wlo[(size_t)m * 262144 + e] = lo;
}

// ---------------------------------------------------------------------------
// GEMM: C[m,n] = sum_k A[m*lda+k] * W[n*ldw+k] + bias[n]   (fp32, unchanged)
// ---------------------------------------------------------------------------
__global__ __launch_bounds__(256) void gemm_nt(
    const float* __restrict__ A, int lda,
    const float* __restrict__ W, int ldw,
    const float* __restrict__ bias,
    float* __restrict__ C, int ldc,
    int M, int N, int K)
{
    __shared__ float As[16][68];
    __shared__ float Ws[16][68];
    const int tid = threadIdx.x;
    const int bm = blockIdx.y * 64;
    const int bn = blockIdx.x * 64;
    const int tx = tid & 15, ty = tid >> 4;
    const int lr = tid >> 2;
    const int lc = (tid & 3) << 2;
    float acc[4][4];
    #pragma unroll
    for (int i = 0; i < 4; ++i)
        #pragma unroll
        for (int j = 0; j < 4; ++j) acc[i][j] = 0.f;

    for (int k0 = 0; k0 < K; k0 += 16) {
        const float4 av = *(const float4*)(A + (size_t)(bm + lr) * lda + k0 + lc);
        const float4 wv = *(const float4*)(W + (size_t)(bn + lr) * ldw + k0 + lc);
        As[lc + 0][lr] = av.x; As[lc + 1][lr] = av.y; As[lc + 2][lr] = av.z; As[lc + 3][lr] = av.w;
        Ws[lc + 0][lr] = wv.x; Ws[lc + 1][lr] = wv.y; Ws[lc + 2][lr] = wv.z; Ws[lc + 3][lr] = wv.w;
        __syncthreads();
        #pragma unroll
        for (int k = 0; k < 16; ++k) {
            const float4 a = *(const float4*)&As[k][ty * 4];
            const float4 b = *(const float4*)&Ws[k][tx * 4];
            const float a_[4] = {a.x, a.y, a.z, a.w};
            const float b_[4] = {b.x, b.y, b.z, b.w};
            #pragma unroll
            for (int i = 0; i < 4; ++i)
                #pragma unroll
                for (int j = 0; j < 4; ++j)
                    acc[i][j] = fmaf(a_[i], b_[j], acc[i][j]);
        }
        __syncthreads();
    }
    #pragma unroll
    for (int i = 0; i < 4; ++i) {
        float4 o;
        o.x = acc[i][0] + bias[bn + tx * 4 + 0];
        o.y = acc[i][1] + bias[bn + tx * 4 + 1];
        o.z = acc[i][2] + bias[bn + tx * 4 + 2];
        o.w = acc[i][3] + bias[bn + tx * 4 + 3];
        *(float4*)(C + (size_t)(bm + ty * 4 + i) * ldc + bn + tx * 4) = o;
    }
}

// ---------------------------------------------------------------------------
// One global time step for ALL 56 runs. Grid = 224 WGs: (run rid, col-quarter q).
// z[64,256-slice] = xg[:,t,slice] + h @ whhT(slice), via MFMA bf16 x3
// (hi*hi + hi*lo + lo*hi ~= fp32). h carried in A-frag-linear bf16 hi/lo
// global buffers, double-buffered by step parity (slot s&1 read, (s+1)&1 write).
// c / running-max fp32 state owned by exactly one lane -> race-free.
// run ids: 0 L1 fwd full | 1 L1 bwd full | 2..26 bwd prefix len 1..25 |
//          27..51 fwd suffix len 1..25 | 52..55 L2 (r2f,r2b,r3f,r3b)
// ---------------------------------------------------------------------------
__global__ __launch_bounds__(256) void lstm_step(
    const int s,
    const float* __restrict__ xgf, const float* __restrict__ xgb,
    const float* __restrict__ xg2,
    const u16* __restrict__ Whi, const u16* __restrict__ Wlo,
    u16* __restrict__ hHi, u16* __restrict__ hLo,
    float* __restrict__ c_st, float* __restrict__ mx_st,
    float* __restrict__ out_pre, float* __restrict__ out_suf,
    float* __restrict__ r4buf)
{
    __shared__ u16 hh[16384];   // 32 KB: h hi, A-frag-linear
    __shared__ u16 hl[16384];   // 32 KB: h lo

    const int wg  = blockIdx.x;
    const int rid = wg >> 2;
    const int q   = wg & 3;

    const float* xg; int wmat, t, ns, mode, len = 0, part = 0;
    if (rid == 0)      { mode = 0; ns = 32; t = s;      xg = xgf; wmat = 0; }
    else if (rid == 1) { mode = 1; ns = 32; t = 31 - s; xg = xgb; wmat = 1; }
    else if (rid < 27) { mode = 2; len = rid - 1;  ns = len;      t = len - 1 - s; xg = xgb; wmat = 1; }
    else if (rid < 52) { mode = 3; len = rid - 26; ns = 32 - len; t = len + s;     xg = xgf; wmat = 0; }
    else { mode = 4; part = rid - 52; ns = 32;
           xg = xg2 + (size_t)part * ((size_t)BB * TT * ZN);
           wmat = 2 + (part & 1); t = (part & 1) ? 31 - s : s; }
    if (s >= ns) return;

    const int tid = threadIdx.x;
    const int w = tid >> 6;     // wave 0..3 -> 16-col sub-slice
    const int l = tid & 63;

    f32x4 acc[4][4];
    #pragma unroll
    for (int a = 0; a < 4; ++a)
        #pragma unroll
        for (int b = 0; b < 4; ++b) acc[a][b] = (f32x4){0.f, 0.f, 0.f, 0.f};

    const size_t HRUN = 16384;
    const size_t HSLOT = 56 * HRUN;

    if (s > 0) {
        // stage previous h (A-frag-linear) into LDS, linear copy
        const uint4* srcH = (const uint4*)(hHi + (size_t)(s & 1) * HSLOT + rid * HRUN);
        const uint4* srcL = (const uint4*)(hLo + (size_t)(s & 1) * HSLOT + rid * HRUN);
        uint4* dH = (uint4*)hh; uint4* dL = (uint4*)hl;
        #pragma unroll
        for (int p = 0; p < 8; ++p) {
            dH[tid + 256 * p] = srcH[tid + 256 * p];
            dL[tid + 256 * p] = srcL[tid + 256 * p];
        }
        __syncthreads();

        const u16* WH = Whi + (size_t)wmat * 262144;
        const u16* WL = Wlo + (size_t)wmat * 262144;
        for (int kt = 0; kt < 8; ++kt) {
            bfrag ah[4], al[4], bh[4], bl[4];
            #pragma unroll
            for (int mt = 0; mt < 4; ++mt) {
                const int off = ((kt * 4 + mt) * 64 + l) * 8;
                ah[mt] = *(const bfrag*)&hh[off];
                al[mt] = *(const bfrag*)&hl[off];
            }
            #pragma unroll
            for (int g = 0; g < 4; ++g) {
                const int nt = g * 16 + q * 4 + w;
                const size_t off = (((size_t)kt * 64 + nt) * 64 + l) * 8;
                bh[g] = *(const bfrag*)(WH + off);
                bl[g] = *(const bfrag*)(WL + off);
            }
            #pragma unroll
            for (int mt = 0; mt < 4; ++mt)
                #pragma unroll
                for (int g = 0; g < 4; ++g) {
                    acc[mt][g] = __builtin_amdgcn_mfma_f32_16x16x32_bf16(ah[mt], bh[g], acc[mt][g], 0, 0, 0);
                    acc[mt][g] = __builtin_amdgcn_mfma_f32_16x16x32_bf16(ah[mt], bl[g], acc[mt][g], 0, 0, 0);
                    acc[mt][g] = __builtin_amdgcn_mfma_f32_16x16x32_bf16(al[mt], bh[g], acc[mt][g], 0, 0, 0);
                }
        }
    }

    // ------------------ gates + state update + outputs ------------------
    const int cl  = l & 15;
    const int hc  = q * 64 + w * 16 + cl;           // h column this lane owns
    const int kt2 = hc >> 5, i2 = hc & 7, lhi = (hc >> 3) & 3;
    u16* hWH = hHi + (size_t)((s + 1) & 1) * HSLOT + rid * HRUN;
    u16* hWL = hLo + (size_t)((s + 1) & 1) * HSLOT + rid * HRUN;
    const int rsub = (l >> 4) << 2;                 // row sub-offset within 16

    #pragma unroll
    for (int mt = 0; mt < 4; ++mt) {
        #pragma unroll
        for (int reg = 0; reg < 4; ++reg) {
            const int row = mt * 16 + rsub + reg;   // batch index 0..63
            const size_t xb = ((size_t)row * TT + t) * ZN + hc;
            const float zi = acc[mt][0][reg] + xg[xb];
            const float zf = acc[mt][1][reg] + xg[xb + 256];
            const float zg = acc[mt][2][reg] + xg[xb + 512];
            const float zo = acc[mt][3][reg] + xg[xb + 768];
            const size_t st = ((size_t)rid * 64 + row) * HH + hc;
            const float cprev = (s == 0) ? 0.f : c_st[st];
            const float c2 = sigm_(zf) * cprev + sigm_(zi) * tanh_(zg);
            const float h2 = sigm_(zo) * tanh_(c2);
            c_st[st] = c2;

            // h writeback in A-frag-linear bf16 hi/lo (for next step's MFMA)
            const u16 uh = f2bf(h2);
            const u16 ul = f2bf(h2 - bf2f(uh));
            const size_t hidx = ((size_t)(kt2 * 4 + mt) * 64 + lhi * 16 + rsub + reg) * 8 + i2;
            hWH[hidx] = uh;
            hWL[hidx] = ul;

            if (mode != 4) {
                const float m2 = fmaxf((s == 0) ? -3.4e38f : mx_st[st], h2);
                mx_st[st] = m2;
                if (mode == 0) {
                    if (t <= 24)
                        out_pre[((size_t)t * BB + row) * (2 * HH) + hc] = m2;
                } else if (mode == 1) {
                    if (t >= 1 && t <= 25)
                        out_suf[((size_t)(t - 1) * BB + row) * (2 * HH) + HH + hc] = m2;
                } else if (mode == 2) {
                    if (s == ns - 1)
                        out_pre[((size_t)(len - 1) * BB + row) * (2 * HH) + HH + hc] = m2;
                } else {
                    if (s == ns - 1)
                        out_suf[((size_t)(len - 1) * BB + row) * (2 * HH) + hc] = m2;
                }
            } else {
                r4buf[((size_t)row * TT + t) * ZN + part * HH + hc] = h2;
            }
        }
    }
}

// ---------------------------------------------------------------------------
extern "C" void kernel_launch(void* const* d_in, const int* in_sizes, int n_in,
                              void* d_out, int out_size, void* d_ws, size_t ws_size,
                              hipStream_t stream)
{
    const float* x    = (const float*)d_in[0];
    const float* wif  = (const float*)d_in[1];
    const float* whf  = (const float*)d_in[2];
    const float* bf   = (const float*)d_in[3];
    const float* wib  = (const float*)d_in[4];
    const float* whb  = (const float*)d_in[5];
    const float* bb   = (const float*)d_in[6];
    const float* w2if = (const float*)d_in[7];
    const float* w2hf = (const float*)d_in[8];
    const float* b2f  = (const float*)d_in[9];
    const float* w2ib = (const float*)d_in[10];
    const float* w2hb = (const float*)d_in[11];
    const float* b2b  = (const float*)d_in[12];
    const float* wl   = (const float*)d_in[13];
    const float* bl   = (const float*)d_in[14];

    const size_t XG = (size_t)BB * TT * ZN;          // 2,097,152 floats
    float* xgf   = (float*)d_ws;
    float* xgb   = xgf + XG;
    float* xg2   = xgb + XG;                         // 4 consecutive arrays
    float* r4    = xg2 + 4 * XG;
    float* c_st  = r4 + XG;                          // 56*64*256
    float* mx_st = c_st + (size_t)56 * 64 * HH;
    u16*   Whi   = (u16*)(mx_st + (size_t)56 * 64 * HH);
    u16*   Wlo   = Whi + (size_t)4 * 262144;
    u16*   hHi   = Wlo + (size_t)4 * 262144;         // 2 slots x 56 x 16384
    u16*   hLo   = hHi + (size_t)2 * 56 * 16384;

    float* outp    = (float*)d_out;
    float* out_pre = outp + (size_t)BB * TT * OO;
    float* out_suf = out_pre + (size_t)NPRE * BB * (2 * HH);

    // 1. one-time weight conversion to MFMA-B-fragment bf16 hi/lo
    prep_weights<<<dim3(1024, 4), 256, 0, stream>>>(whf, whb, w2hf, w2hb, Whi, Wlo);

    // 2. input-gate activation GEMMs (mask-independent: computed once)
    const dim3 blk(256);
    gemm_nt<<<dim3(16, 32), blk, 0, stream>>>(x, II, wif, II, bf, xgf, ZN, BB * TT, ZN, II);
    gemm_nt<<<dim3(16, 32), blk, 0, stream>>>(x, II, wib, II, bb, xgb, ZN, BB * TT, ZN, II);
    gemm_nt<<<dim3(16, 32), blk, 0, stream>>>(x,      II, w2if, HH, b2f, xg2 + 0 * XG, ZN, BB * TT, ZN, HH);
    gemm_nt<<<dim3(16, 32), blk, 0, stream>>>(x,      II, w2ib, HH, b2b, xg2 + 1 * XG, ZN, BB * TT, ZN, HH);
    gemm_nt<<<dim3(16, 32), blk, 0, stream>>>(x + HH, II, w2if, HH, b2f, xg2 + 2 * XG, ZN, BB * TT, ZN, HH);
    gemm_nt<<<dim3(16, 32), blk, 0, stream>>>(x + HH, II, w2ib, HH, b2b, xg2 + 3 * XG, ZN, BB * TT, ZN, HH);

    // 3. 32 global time steps; stream order serializes the recurrence
    for (int s = 0; s < 32; ++s)
        lstm_step<<<dim3(224), blk, 0, stream>>>(s, xgf, xgb, xg2, Whi, Wlo,
                                                 hHi, hLo, c_st, mx_st,
                                                 out_pre, out_suf, r4);

    // 4. final projection: output = r4 @ wl^T + bl
    gemm_nt<<<dim3(8, 32), blk, 0, stream>>>(r4, ZN, wl, ZN, bl, outp, OO, BB * TT, OO, ZN);
}

// Round 3
// 855.918 us; speedup vs baseline: 3.0607x; 1.0802x over previous
//
#include <hip/hip_runtime.h>
#include <math.h>

#define BB 64
#define TT 32
#define II 512
#define HH 256
#define ZN 1024   // 4*H
#define OO 512
#define NPRE 25

typedef unsigned short u16;
typedef short bfrag __attribute__((ext_vector_type(8)));   // 8 bf16 (4 VGPRs)
typedef float f32x4 __attribute__((ext_vector_type(4)));

__device__ __forceinline__ float sigm_(float x) { return 1.f / (1.f + __expf(-x)); }
__device__ __forceinline__ float tanh_(float x) { return 1.f - 2.f / (__expf(2.f * x) + 1.f); }

__device__ __forceinline__ u16 f2bf(float x) {
    union { float f; unsigned u; } v; v.f = x;
    unsigned r = v.u + 0x7fffu + ((v.u >> 16) & 1u);   // RNE
    return (u16)(r >> 16);
}
__device__ __forceinline__ float bf2f(u16 b) {
    union { unsigned u; float f; } v; v.u = ((unsigned)b) << 16; return v.f;
}

// ---------------------------------------------------------------------------
// Fragment prep: src fp32 [D][ld] row-major -> fragment-linear bf16 hi/lo.
//   idx = ((kt*T + t)*64 + l)*8 + i ; d = t*16 + (l&15) ; k = kt*32 + ((l>>4)<<3) + i
// Same formula serves MFMA A-operand (d = row) and B-operand (d = col of W^T).
// grid: (2*T, KT), 256 threads.  T inferred from gridDim.x.
// ---------------------------------------------------------------------------
__global__ __launch_bounds__(256) void prep_frag(
    const float* __restrict__ src, int ld,
    u16* __restrict__ hi, u16* __restrict__ lo)
{
    const int T  = gridDim.x >> 1;
    const int e2 = blockIdx.x * 256 + threadIdx.x;   // within one kt-slab
    const int kt = blockIdx.y;
    const int i = e2 & 7, l = (e2 >> 3) & 63, t = e2 >> 9;
    const int d = t * 16 + (l & 15);
    const int k = kt * 32 + ((l >> 4) << 3) + i;
    const float v = src[(size_t)d * ld + k];
    const u16 h = f2bf(v);
    const size_t o = (size_t)kt * ((size_t)T * 512) + e2;
    hi[o] = h;
    lo[o] = f2bf(v - bf2f(h));
}

// ---------------------------------------------------------------------------
// Register-fragment MFMA GEMM (bf16 x3 ~= fp32):
//   C[m,n] = sum_k A[m,k]*B[n,k] + bias[n]
// A,B pre-converted to fragment-linear hi/lo. No LDS, no barriers.
// WG = 256 threads: 64 rows x 256 cols tile; wave w owns 4 contiguous 16-col
// tiles. 2-stage prefetch over K-slabs (KT must be even).
// grid: (N/256, M/64)
// ---------------------------------------------------------------------------
__global__ __launch_bounds__(256) void gemm_mfma(
    const u16* __restrict__ Ahi, const u16* __restrict__ Alo, const int MT, const int kt0,
    const u16* __restrict__ Bhi, const u16* __restrict__ Blo, const int NT,
    const float* __restrict__ bias,
    float* __restrict__ C, const int ldc, const int KT)
{
    const int tid = threadIdx.x;
    const int w = tid >> 6, l = tid & 63;
    const int mt0 = blockIdx.y * 4;
    const int nt0 = blockIdx.x * 16 + w * 4;

    f32x4 acc[4][4];
    #pragma unroll
    for (int a = 0; a < 4; ++a)
        #pragma unroll
        for (int b = 0; b < 4; ++b) acc[a][b] = (f32x4){0.f, 0.f, 0.f, 0.f};

    bfrag ah0[4], al0[4], bh0[4], bl0[4];
    bfrag ah1[4], al1[4], bh1[4], bl1[4];

#define LOADF(AH, AL, BH, BL, KIDX) do {                                          \
    const int kk_ = (KIDX);                                                      \
    _Pragma("unroll") for (int mt = 0; mt < 4; ++mt) {                            \
        const size_t oa = (((size_t)(kt0 + kk_) * MT + mt0 + mt) * 64 + l) * 8;   \
        AH[mt] = *(const bfrag*)(Ahi + oa); AL[mt] = *(const bfrag*)(Alo + oa); } \
    _Pragma("unroll") for (int j = 0; j < 4; ++j) {                               \
        const size_t ob = (((size_t)kk_ * NT + nt0 + j) * 64 + l) * 8;            \
        BH[j] = *(const bfrag*)(Bhi + ob); BL[j] = *(const bfrag*)(Blo + ob); }   \
} while (0)

#define MFMAS(AH, AL, BH, BL) do {                                                \
    _Pragma("unroll") for (int mt = 0; mt < 4; ++mt)                              \
    _Pragma("unroll") for (int j = 0; j < 4; ++j) {                               \
        acc[mt][j] = __builtin_amdgcn_mfma_f32_16x16x32_bf16(AH[mt], BH[j], acc[mt][j], 0, 0, 0); \
        acc[mt][j] = __builtin_amdgcn_mfma_f32_16x16x32_bf16(AH[mt], BL[j], acc[mt][j], 0, 0, 0); \
        acc[mt][j] = __builtin_amdgcn_mfma_f32_16x16x32_bf16(AL[mt], BH[j], acc[mt][j], 0, 0, 0); } \
} while (0)

    LOADF(ah0, al0, bh0, bl0, 0);
    for (int kt = 0; kt < KT; kt += 2) {
        LOADF(ah1, al1, bh1, bl1, kt + 1);
        MFMAS(ah0, al0, bh0, bl0);
        if (kt + 2 < KT) LOADF(ah0, al0, bh0, bl0, kt + 2);
        MFMAS(ah1, al1, bh1, bl1);
    }
#undef LOADF
#undef MFMAS

    const int rsub = (l >> 4) << 2;
    #pragma unroll
    for (int j = 0; j < 4; ++j) {
        const int col = (nt0 + j) * 16 + (l & 15);
        const float bv = bias[col];
        #pragma unroll
        for (int mt = 0; mt < 4; ++mt)
            #pragma unroll
            for (int reg = 0; reg < 4; ++reg)
                C[(size_t)((mt0 + mt) * 16 + rsub + reg) * ldc + col] = acc[mt][j][reg] + bv;
    }
}

// ---------------------------------------------------------------------------
// One global time step for ALL 56 runs. Grid = 224 WGs: (run rid, col-quarter q).
// Software-pipelined: B-fragments for kt+1 prefetched during kt's MFMAs.
// run ids: 0 L1 fwd full | 1 L1 bwd full | 2..26 bwd prefix len 1..25 |
//          27..51 fwd suffix len 1..25 | 52..55 L2 (r2f,r2b,r3f,r3b)
// ---------------------------------------------------------------------------
__global__ __launch_bounds__(256) void lstm_step(
    const int s,
    const float* __restrict__ xgf, const float* __restrict__ xgb,
    const float* __restrict__ xg2,
    const u16* __restrict__ Whi, const u16* __restrict__ Wlo,
    u16* __restrict__ hHi, u16* __restrict__ hLo,
    float* __restrict__ c_st, float* __restrict__ mx_st,
    float* __restrict__ out_pre, float* __restrict__ out_suf,
    float* __restrict__ r4buf)
{
    __shared__ u16 hh[16384];   // 32 KB: h hi, A-frag-linear
    __shared__ u16 hl[16384];   // 32 KB: h lo

    const int wg  = blockIdx.x;
    const int rid = wg >> 2;
    const int q   = wg & 3;

    const float* xg; int wmat, t, ns, mode, len = 0, part = 0;
    if (rid == 0)      { mode = 0; ns = 32; t = s;      xg = xgf; wmat = 0; }
    else if (rid == 1) { mode = 1; ns = 32; t = 31 - s; xg = xgb; wmat = 1; }
    else if (rid < 27) { mode = 2; len = rid - 1;  ns = len;      t = len - 1 - s; xg = xgb; wmat = 1; }
    else if (rid < 52) { mode = 3; len = rid - 26; ns = 32 - len; t = len + s;     xg = xgf; wmat = 0; }
    else { mode = 4; part = rid - 52; ns = 32;
           xg = xg2 + (size_t)part * ((size_t)BB * TT * ZN);
           wmat = 2 + (part & 1); t = (part & 1) ? 31 - s : s; }
    if (s >= ns) return;

    const int tid = threadIdx.x;
    const int w = tid >> 6;     // wave 0..3 -> 16-col sub-slice
    const int l = tid & 63;
    const int q4w = q * 4 + w;

    f32x4 acc[4][4];
    #pragma unroll
    for (int a = 0; a < 4; ++a)
        #pragma unroll
        for (int b = 0; b < 4; ++b) acc[a][b] = (f32x4){0.f, 0.f, 0.f, 0.f};

    const size_t HRUN = 16384;
    const size_t HSLOT = 56 * HRUN;

    if (s > 0) {
        // stage previous h (A-frag-linear) into LDS, linear copy
        const uint4* srcH = (const uint4*)(hHi + (size_t)(s & 1) * HSLOT + rid * HRUN);
        const uint4* srcL = (const uint4*)(hLo + (size_t)(s & 1) * HSLOT + rid * HRUN);
        uint4* dH = (uint4*)hh; uint4* dL = (uint4*)hl;
        #pragma unroll
        for (int p = 0; p < 8; ++p) {
            dH[tid + 256 * p] = srcH[tid + 256 * p];
            dL[tid + 256 * p] = srcL[tid + 256 * p];
        }
        __syncthreads();

        const u16* WH = Whi + (size_t)wmat * 262144;
        const u16* WL = Wlo + (size_t)wmat * 262144;
        bfrag bh0[4], bl0[4], bh1[4], bl1[4];
        #pragma unroll
        for (int g = 0; g < 4; ++g) {
            const size_t ob = (((size_t)g * 16 + q4w) * 64 + l) * 8;
            bh0[g] = *(const bfrag*)(WH + ob);
            bl0[g] = *(const bfrag*)(WL + ob);
        }

#define STEPK(KT_, BHc, BLc, BHn, BLn) do {                                        \
    if ((KT_) < 7) {                                                              \
        _Pragma("unroll") for (int g = 0; g < 4; ++g) {                           \
            const size_t ob = ((((size_t)(KT_) + 1) * 64 + g * 16 + q4w) * 64 + l) * 8; \
            BHn[g] = *(const bfrag*)(WH + ob); BLn[g] = *(const bfrag*)(WL + ob); } } \
    bfrag ah[4], al[4];                                                           \
    _Pragma("unroll") for (int mt = 0; mt < 4; ++mt) {                            \
        const int oa = (((KT_) * 4 + mt) * 64 + l) * 8;                           \
        ah[mt] = *(const bfrag*)&hh[oa]; al[mt] = *(const bfrag*)&hl[oa]; }       \
    _Pragma("unroll") for (int mt = 0; mt < 4; ++mt)                              \
    _Pragma("unroll") for (int g = 0; g < 4; ++g) {                               \
        acc[mt][g] = __builtin_amdgcn_mfma_f32_16x16x32_bf16(ah[mt], BHc[g], acc[mt][g], 0, 0, 0); \
        acc[mt][g] = __builtin_amdgcn_mfma_f32_16x16x32_bf16(ah[mt], BLc[g], acc[mt][g], 0, 0, 0); \
        acc[mt][g] = __builtin_amdgcn_mfma_f32_16x16x32_bf16(al[mt], BHc[g], acc[mt][g], 0, 0, 0); } \
} while (0)

        STEPK(0, bh0, bl0, bh1, bl1);
        STEPK(1, bh1, bl1, bh0, bl0);
        STEPK(2, bh0, bl0, bh1, bl1);
        STEPK(3, bh1, bl1, bh0, bl0);
        STEPK(4, bh0, bl0, bh1, bl1);
        STEPK(5, bh1, bl1, bh0, bl0);
        STEPK(6, bh0, bl0, bh1, bl1);
        STEPK(7, bh1, bl1, bh0, bl0);
#undef STEPK
    }

    // ------------------ gates + state update + outputs ------------------
    const int cl  = l & 15;
    const int hc  = q * 64 + w * 16 + cl;           // h column this lane owns
    const int kt2 = hc >> 5, i2 = hc & 7, lhi = (hc >> 3) & 3;
    u16* hWH = hHi + (size_t)((s + 1) & 1) * HSLOT + rid * HRUN;
    u16* hWL = hLo + (size_t)((s + 1) & 1) * HSLOT + rid * HRUN;
    const int rsub = (l >> 4) << 2;                 // row sub-offset within 16

    #pragma unroll
    for (int mt = 0; mt < 4; ++mt) {
        #pragma unroll
        for (int reg = 0; reg < 4; ++reg) {
            const int row = mt * 16 + rsub + reg;   // batch index 0..63
            const size_t xb = ((size_t)row * TT + t) * ZN + hc;
            const float zi = acc[mt][0][reg] + xg[xb];
            const float zf = acc[mt][1][reg] + xg[xb + 256];
            const float zg = acc[mt][2][reg] + xg[xb + 512];
            const float zo = acc[mt][3][reg] + xg[xb + 768];
            const size_t st = ((size_t)rid * 64 + row) * HH + hc;
            const float cprev = (s == 0) ? 0.f : c_st[st];
            const float c2 = sigm_(zf) * cprev + sigm_(zi) * tanh_(zg);
            const float h2 = sigm_(zo) * tanh_(c2);
            c_st[st] = c2;

            // h writeback in A-frag-linear bf16 hi/lo (for next step's MFMA)
            const u16 uh = f2bf(h2);
            const u16 ul = f2bf(h2 - bf2f(uh));
            const size_t hidx = ((size_t)(kt2 * 4 + mt) * 64 + lhi * 16 + rsub + reg) * 8 + i2;
            hWH[hidx] = uh;
            hWL[hidx] = ul;

            if (mode != 4) {
                const float m2 = fmaxf((s == 0) ? -3.4e38f : mx_st[st], h2);
                mx_st[st] = m2;
                if (mode == 0) {
                    if (t <= 24)
                        out_pre[((size_t)t * BB + row) * (2 * HH) + hc] = m2;
                } else if (mode == 1) {
                    if (t >= 1 && t <= 25)
                        out_suf[((size_t)(t - 1) * BB + row) * (2 * HH) + HH + hc] = m2;
                } else if (mode == 2) {
                    if (s == ns - 1)
                        out_pre[((size_t)(len - 1) * BB + row) * (2 * HH) + HH + hc] = m2;
                } else {
                    if (s == ns - 1)
                        out_suf[((size_t)(len - 1) * BB + row) * (2 * HH) + hc] = m2;
                }
            } else {
                r4buf[((size_t)row * TT + t) * ZN + part * HH + hc] = h2;
            }
        }
    }
}

// ---------------------------------------------------------------------------
extern "C" void kernel_launch(void* const* d_in, const int* in_sizes, int n_in,
                              void* d_out, int out_size, void* d_ws, size_t ws_size,
                              hipStream_t stream)
{
    const float* x    = (const float*)d_in[0];
    const float* wif  = (const float*)d_in[1];
    const float* whf  = (const float*)d_in[2];
    const float* bf   = (const float*)d_in[3];
    const float* wib  = (const float*)d_in[4];
    const float* whb  = (const float*)d_in[5];
    const float* bb   = (const float*)d_in[6];
    const float* w2if = (const float*)d_in[7];
    const float* w2hf = (const float*)d_in[8];
    const float* b2f  = (const float*)d_in[9];
    const float* w2ib = (const float*)d_in[10];
    const float* w2hb = (const float*)d_in[11];
    const float* b2b  = (const float*)d_in[12];
    const float* wl   = (const float*)d_in[13];
    const float* bl   = (const float*)d_in[14];

    const size_t XG = (size_t)BB * TT * ZN;          // 2,097,152 floats
    float* xgf   = (float*)d_ws;
    float* xgb   = xgf + XG;
    float* xg2   = xgb + XG;                         // 4 consecutive arrays
    float* r4    = xg2 + 4 * XG;
    float* c_st  = r4 + XG;                          // 56*64*256
    float* mx_st = c_st + (size_t)56 * BB * HH;

    u16* p = (u16*)(mx_st + (size_t)56 * BB * HH);
    u16* WhiR = p;  p += (size_t)4 * 262144;
    u16* WloR = p;  p += (size_t)4 * 262144;
    u16* hHi  = p;  p += (size_t)2 * 56 * 16384;
    u16* hLo  = p;  p += (size_t)2 * 56 * 16384;
    u16* xAh  = p;  p += (size_t)2048 * 512;
    u16* xAl  = p;  p += (size_t)2048 * 512;
    u16* r4Ah = p;  p += (size_t)2048 * 1024;
    u16* r4Al = p;  p += (size_t)2048 * 1024;
    u16* wifBh = p; p += (size_t)1024 * 512;
    u16* wifBl = p; p += (size_t)1024 * 512;
    u16* wibBh = p; p += (size_t)1024 * 512;
    u16* wibBl = p; p += (size_t)1024 * 512;
    u16* w2ifBh = p; p += (size_t)1024 * 256;
    u16* w2ifBl = p; p += (size_t)1024 * 256;
    u16* w2ibBh = p; p += (size_t)1024 * 256;
    u16* w2ibBl = p; p += (size_t)1024 * 256;
    u16* wlBh = p;  p += (size_t)512 * 1024;
    u16* wlBl = p;  p += (size_t)512 * 1024;

    float* outp    = (float*)d_out;
    float* out_pre = outp + (size_t)BB * TT * OO;
    float* out_suf = out_pre + (size_t)NPRE * BB * (2 * HH);

    // 1. fragment preps (recurrence weights / x / GEMM weights)
    prep_frag<<<dim3(128, 8),  256, 0, stream>>>(whf,  HH, WhiR + 0 * 262144, WloR + 0 * 262144);
    prep_frag<<<dim3(128, 8),  256, 0, stream>>>(whb,  HH, WhiR + 1 * 262144, WloR + 1 * 262144);
    prep_frag<<<dim3(128, 8),  256, 0, stream>>>(w2hf, HH, WhiR + 2 * 262144, WloR + 2 * 262144);
    prep_frag<<<dim3(128, 8),  256, 0, stream>>>(w2hb, HH, WhiR + 3 * 262144, WloR + 3 * 262144);
    prep_frag<<<dim3(256, 16), 256, 0, stream>>>(x,    II, xAh, xAl);        // T=128, K=512
    prep_frag<<<dim3(128, 16), 256, 0, stream>>>(wif,  II, wifBh, wifBl);    // T=64,  K=512
    prep_frag<<<dim3(128, 16), 256, 0, stream>>>(wib,  II, wibBh, wibBl);
    prep_frag<<<dim3(128, 8),  256, 0, stream>>>(w2if, HH, w2ifBh, w2ifBl);  // T=64,  K=256
    prep_frag<<<dim3(128, 8),  256, 0, stream>>>(w2ib, HH, w2ibBh, w2ibBl);
    prep_frag<<<dim3(64, 32),  256, 0, stream>>>(wl,   ZN, wlBh, wlBl);      // T=32,  K=1024

    // 2. input-gate activation GEMMs (mask-independent: computed once)
    gemm_mfma<<<dim3(4, 32), 256, 0, stream>>>(xAh, xAl, 128, 0, wifBh, wifBl, 64, bf, xgf, ZN, 16);
    gemm_mfma<<<dim3(4, 32), 256, 0, stream>>>(xAh, xAl, 128, 0, wibBh, wibBl, 64, bb, xgb, ZN, 16);
    gemm_mfma<<<dim3(4, 32), 256, 0, stream>>>(xAh, xAl, 128, 0, w2ifBh, w2ifBl, 64, b2f, xg2 + 0 * XG, ZN, 8);
    gemm_mfma<<<dim3(4, 32), 256, 0, stream>>>(xAh, xAl, 128, 0, w2ibBh, w2ibBl, 64, b2b, xg2 + 1 * XG, ZN, 8);
    gemm_mfma<<<dim3(4, 32), 256, 0, stream>>>(xAh, xAl, 128, 8, w2ifBh, w2ifBl, 64, b2f, xg2 + 2 * XG, ZN, 8);
    gemm_mfma<<<dim3(4, 32), 256, 0, stream>>>(xAh, xAl, 128, 8, w2ibBh, w2ibBl, 64, b2b, xg2 + 3 * XG, ZN, 8);

    // 3. 32 global time steps; stream order serializes the recurrence
    for (int s = 0; s < 32; ++s)
        lstm_step<<<dim3(224), 256, 0, stream>>>(s, xgf, xgb, xg2, WhiR, WloR,
                                                 hHi, hLo, c_st, mx_st,
                                                 out_pre, out_suf, r4);

    // 4. final projection: output = r4 @ wl^T + bl
    prep_frag<<<dim3(256, 32), 256, 0, stream>>>(r4, ZN, r4Ah, r4Al);        // T=128, K=1024
    gemm_mfma<<<dim3(2, 32), 256, 0, stream>>>(r4Ah, r4Al, 128, 0, wlBh, wlBl, 32, bl, outp, OO, 32);
}